// Round 7
// baseline (593.660 us; speedup 1.0000x reference)
//
#include <hip/hip_runtime.h>
#include <cstdint>
#include <math.h>

#define F_IN 512
#define HID  16
#define NCLS 40
#define OUT_STRIDE 20
#define TB   128   // nodes per dst-bucket (bucket = dst >> 7)
#define NBA  256   // partition-phase blocks

// ---------- A1: per-block bucket histogram (nt-loads: single-use stream) ----------
__global__ __launch_bounds__(256) void k_a1(const int* __restrict__ dst,
                                            int* __restrict__ cnt,
                                            int E, int NB, int chunk) {
    __shared__ int h[1024];
    int t = threadIdx.x;
    for (int b = t; b < NB; b += 256) h[b] = 0;
    __syncthreads();
    int e0 = blockIdx.x * chunk, e1 = min(E, e0 + chunk);
    for (int e = e0 + t; e < e1; e += 256) {
        int d = __builtin_nontemporal_load(&dst[e]);
        atomicAdd(&h[d >> 7], 1);
    }
    __syncthreads();
    for (int b = t; b < NB; b += 256) cnt[(size_t)blockIdx.x * NB + b] = h[b];
}

// ---------- A2a: per-bucket exclusive scan across blocks ----------
__global__ __launch_bounds__(NBA) void k_a2a(const int* __restrict__ cnt,
                                             int* __restrict__ offsT,
                                             int* __restrict__ total, int NB) {
    __shared__ int s[NBA];
    int t = threadIdx.x, b = blockIdx.x;
    int v = cnt[(size_t)t * NB + b];
    s[t] = v;
    __syncthreads();
    for (int off = 1; off < NBA; off <<= 1) {
        int tmp = (t >= off) ? s[t - off] : 0;
        __syncthreads();
        s[t] += tmp;
        __syncthreads();
    }
    offsT[(size_t)b * NBA + t] = s[t] - v;
    if (t == NBA - 1) total[b] = s[t];
}

// ---------- A2b: scan bucket totals -> bucket base (+sentinel) ----------
__global__ void k_a2b(const int* __restrict__ total, int* __restrict__ base, int NB) {
    __shared__ int s[1024];
    int t = threadIdx.x;
    int v = (t < NB) ? total[t] : 0;
    s[t] = v;
    __syncthreads();
    for (int off = 1; off < 1024; off <<= 1) {
        int tmp = (t >= off) ? s[t - off] : 0;
        __syncthreads();
        s[t] += tmp;
        __syncthreads();
    }
    if (t < NB) base[t] = s[t] - v;
    if (t == NB - 1) base[NB] = s[t];
}

// ---------- A3: stable partition scatter; per-block contiguous runs ----------
__global__ __launch_bounds__(256) void k_a3(const int* __restrict__ src,
                                            const int* __restrict__ dst,
                                            const int* __restrict__ offsT,
                                            const int* __restrict__ base,
                                            unsigned* __restrict__ bin,
                                            int E, int NB, int chunk) {
    __shared__ int pos[1024];
    int t = threadIdx.x, blk = blockIdx.x;
    for (int b = t; b < NB; b += 256) pos[b] = base[b] + offsT[(size_t)b * NBA + blk];
    __syncthreads();
    int e0 = blk * chunk, e1 = min(E, e0 + chunk);
    for (int e = e0 + t; e < e1; e += 256) {
        int d = __builtin_nontemporal_load(&dst[e]);
        int s = __builtin_nontemporal_load(&src[e]);
        int p = atomicAdd(&pos[d >> 7], 1);
        bin[p] = ((unsigned)s << 7) | (unsigned)(d & (TB - 1));
    }
}

// ---------- Bdeg: bucket-local degree count -> dinv ----------
__global__ __launch_bounds__(256) void k_bdeg(const unsigned* __restrict__ bin,
                                              const int* __restrict__ base,
                                              float* __restrict__ dinv, int N) {
    __shared__ int c[TB];
    int t = threadIdx.x, b = blockIdx.x;
    if (t < TB) c[t] = 0;
    __syncthreads();
    int j0 = base[b], j1 = base[b + 1];
    for (int j = j0 + t; j < j1; j += 256)
        atomicAdd(&c[__builtin_nontemporal_load(&bin[j]) & (TB - 1)], 1);
    __syncthreads();
    int node = b * TB + t;
    if (t < TB && node < N) dinv[node] = rsqrtf((float)c[t] + 1.0f);  // +1 self loop
}

// ---------- GEMM1: h1s[i][c] = (x[i] . W1[:,c]) * dinv[i] (unchanged) ----------
#define KS  4
#define KCH (F_IN / KS)  // 128
__global__ __launch_bounds__(256) void k_gemm1(const float* __restrict__ x,
                                               const float* __restrict__ W1,
                                               const float* __restrict__ dinv,
                                               float* __restrict__ h1s, int n) {
    __shared__ float wlds[F_IN * HID];      // 32 KB
    __shared__ float red[3 * 64 * HID];     // 12 KB
    int t = threadIdx.x;
    int wid = t >> 6;
    int lane = t & 63;

    for (int i = t * 4; i < F_IN * HID; i += 256 * 4)
        *(float4*)&wlds[i] = *(const float4*)&W1[i];
    __syncthreads();

    int row = blockIdx.x * 64 + lane;
    int rclamp = (row < n) ? row : (n - 1);
    const float* xp = x + (size_t)rclamp * F_IN + wid * KCH;
    const float* wp = &wlds[wid * KCH * HID];

    float acc[HID];
#pragma unroll
    for (int c = 0; c < HID; c++) acc[c] = 0.f;

#pragma unroll 8
    for (int k4 = 0; k4 < KCH / 4; k4++) {
        float4 xv = *(const float4*)&xp[k4 * 4];
#pragma unroll
        for (int kk = 0; kk < 4; kk++) {
            float xs = ((const float*)&xv)[kk];
            const float4* wr = (const float4*)&wp[(k4 * 4 + kk) * HID];
#pragma unroll
            for (int cg = 0; cg < 4; cg++) {
                float4 wv = wr[cg];
                acc[cg * 4 + 0] = fmaf(xs, wv.x, acc[cg * 4 + 0]);
                acc[cg * 4 + 1] = fmaf(xs, wv.y, acc[cg * 4 + 1]);
                acc[cg * 4 + 2] = fmaf(xs, wv.z, acc[cg * 4 + 2]);
                acc[cg * 4 + 3] = fmaf(xs, wv.w, acc[cg * 4 + 3]);
            }
        }
    }

    if (wid > 0) {
        float* r = &red[((wid - 1) * 64 + lane) * HID];
#pragma unroll
        for (int cg = 0; cg < 4; cg++)
            *(float4*)&r[cg * 4] = make_float4(acc[cg * 4], acc[cg * 4 + 1],
                                               acc[cg * 4 + 2], acc[cg * 4 + 3]);
    }
    __syncthreads();
    if (wid == 0 && row < n) {
        float dv = dinv[row];
#pragma unroll
        for (int cg = 0; cg < 4; cg++) {
            float4 p0 = *(float4*)&red[(0 * 64 + lane) * HID + cg * 4];
            float4 p1 = *(float4*)&red[(1 * 64 + lane) * HID + cg * 4];
            float4 p2 = *(float4*)&red[(2 * 64 + lane) * HID + cg * 4];
            float4 o;
            o.x = (acc[cg * 4 + 0] + p0.x + p1.x + p2.x) * dv;
            o.y = (acc[cg * 4 + 1] + p0.y + p1.y + p2.y) * dv;
            o.z = (acc[cg * 4 + 2] + p0.z + p1.z + p2.z) * dv;
            o.w = (acc[cg * 4 + 3] + p0.w + p1.w + p2.w) * dv;
            *(float4*)&h1s[(size_t)row * HID + cg * 4] = o;
        }
    }
}

// ---------- Bagg: bucket aggregation; asm-batched loads force MLP ----------
// Each 16-lane group owns a contiguous chunk of the bucket's bin run.
// Per iteration: one asm block = 8 bin loads + wait; one asm block = 8
// independent h1s gathers + wait (compiler cannot serialize inside asm).
__global__ __launch_bounds__(256) void k_bagg(const unsigned* __restrict__ bin,
                                              const int* __restrict__ base,
                                              const float* __restrict__ h1s,
                                              const float* __restrict__ dinv,
                                              const float* __restrict__ b1,
                                              float* __restrict__ z, int N) {
    __shared__ float acc[TB * HID];   // 8 KB
    int t = threadIdx.x, b = blockIdx.x;
    for (int i = t; i < TB * HID; i += 256) acc[i] = 0.f;
    __syncthreads();
    int g = t >> 4, l = t & 15;       // 16 groups x 16 lanes
    int j0 = base[b], j1 = base[b + 1];
    int cnt = j1 - j0;
    int ch = (cnt + 15) >> 4;         // chunk per group (contiguous)
    int jj = j0 + g * ch;
    int jend = jj + ch;
    if (jend > j1) jend = j1;
    if (jj > j1) jj = j1;

    for (; jj + 8 <= jend; jj += 8) {
        unsigned v0, v1, v2, v3, v4, v5, v6, v7;
        asm volatile(
            "global_load_dword %0, %8, off\n\t"
            "global_load_dword %1, %9, off\n\t"
            "global_load_dword %2, %10, off\n\t"
            "global_load_dword %3, %11, off\n\t"
            "global_load_dword %4, %12, off\n\t"
            "global_load_dword %5, %13, off\n\t"
            "global_load_dword %6, %14, off\n\t"
            "global_load_dword %7, %15, off\n\t"
            "s_waitcnt vmcnt(0)"
            : "=&v"(v0), "=&v"(v1), "=&v"(v2), "=&v"(v3),
              "=&v"(v4), "=&v"(v5), "=&v"(v6), "=&v"(v7)
            : "v"(&bin[jj]), "v"(&bin[jj + 1]), "v"(&bin[jj + 2]), "v"(&bin[jj + 3]),
              "v"(&bin[jj + 4]), "v"(&bin[jj + 5]), "v"(&bin[jj + 6]), "v"(&bin[jj + 7])
            : "memory");
        const float* q0 = &h1s[(size_t)(v0 >> 7) * HID + l];
        const float* q1 = &h1s[(size_t)(v1 >> 7) * HID + l];
        const float* q2 = &h1s[(size_t)(v2 >> 7) * HID + l];
        const float* q3 = &h1s[(size_t)(v3 >> 7) * HID + l];
        const float* q4 = &h1s[(size_t)(v4 >> 7) * HID + l];
        const float* q5 = &h1s[(size_t)(v5 >> 7) * HID + l];
        const float* q6 = &h1s[(size_t)(v6 >> 7) * HID + l];
        const float* q7 = &h1s[(size_t)(v7 >> 7) * HID + l];
        float g0, g1, g2, g3, g4, g5, g6, g7;
        asm volatile(
            "global_load_dword %0, %8, off\n\t"
            "global_load_dword %1, %9, off\n\t"
            "global_load_dword %2, %10, off\n\t"
            "global_load_dword %3, %11, off\n\t"
            "global_load_dword %4, %12, off\n\t"
            "global_load_dword %5, %13, off\n\t"
            "global_load_dword %6, %14, off\n\t"
            "global_load_dword %7, %15, off\n\t"
            "s_waitcnt vmcnt(0)"
            : "=&v"(g0), "=&v"(g1), "=&v"(g2), "=&v"(g3),
              "=&v"(g4), "=&v"(g5), "=&v"(g6), "=&v"(g7)
            : "v"(q0), "v"(q1), "v"(q2), "v"(q3),
              "v"(q4), "v"(q5), "v"(q6), "v"(q7)
            : "memory");
        atomicAdd(&acc[(v0 & (TB - 1)) * HID + l], g0);
        atomicAdd(&acc[(v1 & (TB - 1)) * HID + l], g1);
        atomicAdd(&acc[(v2 & (TB - 1)) * HID + l], g2);
        atomicAdd(&acc[(v3 & (TB - 1)) * HID + l], g3);
        atomicAdd(&acc[(v4 & (TB - 1)) * HID + l], g4);
        atomicAdd(&acc[(v5 & (TB - 1)) * HID + l], g5);
        atomicAdd(&acc[(v6 & (TB - 1)) * HID + l], g6);
        atomicAdd(&acc[(v7 & (TB - 1)) * HID + l], g7);
    }
    for (; jj < jend; jj++) {
        unsigned v = bin[jj];
        atomicAdd(&acc[(v & (TB - 1)) * HID + l], h1s[(size_t)(v >> 7) * HID + l]);
    }
    __syncthreads();
    float bl = b1[l];
    for (int r = g; r < TB; r += 16) {
        int node = b * TB + r;
        if (node < N) {
            float dv = dinv[node];
            float pre = dv * (acc[r * HID + l] + h1s[(size_t)node * HID + l]) + bl;
            z[(size_t)node * HID + l] = fmaxf(pre, 0.f) * dv;
        }
    }
}

// ---------- B2: layer-2 aggregation for dst%20==0 only ----------
__global__ __launch_bounds__(256) void k_b2(const unsigned* __restrict__ bin,
                                            const int* __restrict__ base,
                                            const float* __restrict__ z,
                                            float* __restrict__ acc2, int N) {
    __shared__ float a2[TB * HID];
    int t = threadIdx.x, b = blockIdx.x;
    for (int i = t; i < TB * HID; i += 256) a2[i] = 0.f;
    __syncthreads();
    int g = t >> 4, l = t & 15;
    int j0 = base[b], j1 = base[b + 1];
    int node0 = b * TB;
    for (int j = j0 + g; j < j1; j += 16) {
        unsigned v = bin[j];
        int dl = v & (TB - 1);
        if ((node0 + dl) % OUT_STRIDE == 0) {
            int s = v >> 7;
            atomicAdd(&a2[dl * HID + l], z[(size_t)s * HID + l]);
        }
    }
    __syncthreads();
    for (int r = g; r < TB; r += 16) {
        int node = node0 + r;
        if (node < N && node % OUT_STRIDE == 0)
            acc2[(size_t)(node / OUT_STRIDE) * HID + l] = a2[r * HID + l];
    }
}

// ---------- out: matvec @W2 + b2 + log_softmax, wave per out row ----------
__global__ void k_out2(const float* __restrict__ z, const float* __restrict__ acc2,
                       const float* __restrict__ dinv, const float* __restrict__ W2,
                       const float* __restrict__ b2, float* __restrict__ out, int nOut) {
    int lane = threadIdx.x & 63;
    int wv = (blockIdx.x * blockDim.x + threadIdx.x) >> 6;
    if (wv >= nOut) return;
    int node = wv * OUT_STRIDE;
    int c = lane & 15;
    float a = dinv[node] * (acc2[(size_t)wv * HID + c] + z[(size_t)node * HID + c]);

    int jj = lane < NCLS ? lane : 0;
    float v = 0.f;
#pragma unroll
    for (int cc = 0; cc < 16; cc++) {
        float ac = __shfl(a, cc);
        v = fmaf(ac, W2[cc * NCLS + jj], v);
    }
    v += b2[jj];

    float vm = lane < NCLS ? v : -INFINITY;
    for (int off = 1; off < 64; off <<= 1) vm = fmaxf(vm, __shfl_xor(vm, off));
    float ex = lane < NCLS ? expf(v - vm) : 0.f;
    float se = ex;
    for (int off = 1; off < 64; off <<= 1) se += __shfl_xor(se, off);
    float ls = logf(se);
    if (lane < NCLS) out[(size_t)wv * NCLS + lane] = v - vm - ls;
}

// ---------------- host launcher ----------------
extern "C" void kernel_launch(void* const* d_in, const int* in_sizes, int n_in,
                              void* d_out, int out_size, void* d_ws, size_t ws_size,
                              hipStream_t stream) {
    const int E = in_sizes[0] / 2;
    const int N = in_sizes[1] / F_IN;
    const int nOut = (N + OUT_STRIDE - 1) / OUT_STRIDE;
    const int NB = (N + TB - 1) / TB;                 // 782
    const int chunk = (E + NBA - 1) / NBA;

    const int* src = (const int*)d_in[0];
    const int* dst = src + E;
    const float* x  = (const float*)d_in[1];
    const float* W1 = (const float*)d_in[2];
    const float* b1 = (const float*)d_in[3];
    const float* W2 = (const float*)d_in[4];
    const float* b2 = (const float*)d_in[5];
    float* out = (float*)d_out;

    uint8_t* w = (uint8_t*)d_ws;
    size_t off = 0;
    auto carve = [&](size_t bytes) {
        void* p = w + off;
        off += (bytes + 15) & ~(size_t)15;
        return p;
    };
    float*    dinv  = (float*)carve((size_t)N * 4);
    unsigned* bin   = (unsigned*)carve((size_t)E * 4);
    int*      cnt   = (int*)carve((size_t)NBA * NB * 4);
    int*      offsT = (int*)carve((size_t)NB * NBA * 4);
    int*      total = (int*)carve((size_t)NB * 4);
    int*      base  = (int*)carve((size_t)(NB + 1) * 4);
    float*    h1s   = (float*)carve((size_t)N * HID * 4);
    float*    z     = (float*)carve((size_t)N * HID * 4);
    float*    acc2  = (float*)carve((size_t)nOut * HID * 4);
    (void)ws_size; (void)n_in; (void)out_size;

    k_a1 <<<NBA, 256, 0, stream>>>(dst, cnt, E, NB, chunk);
    k_a2a<<<NB, NBA, 0, stream>>>(cnt, offsT, total, NB);
    k_a2b<<<1, 1024, 0, stream>>>(total, base, NB);
    k_a3 <<<NBA, 256, 0, stream>>>(src, dst, offsT, base, bin, E, NB, chunk);
    k_bdeg<<<NB, 256, 0, stream>>>(bin, base, dinv, N);
    k_gemm1<<<(N + 63) / 64, 256, 0, stream>>>(x, W1, dinv, h1s, N);
    k_bagg<<<NB, 256, 0, stream>>>(bin, base, h1s, dinv, b1, z, N);
    k_b2 <<<NB, 256, 0, stream>>>(bin, base, z, acc2, N);
    k_out2<<<(nOut * 64 + 255) / 256, 256, 0, stream>>>(z, acc2, dinv, W2, b2, out, nOut);
}

// Round 8
// 249.962 us; speedup vs baseline: 2.3750x; 2.3750x over previous
//
#include <hip/hip_runtime.h>
#include <cstdint>
#include <math.h>

#define F_IN 512
#define HID  16
#define NCLS 40
#define OUT_STRIDE 20
#define TB   128   // nodes per dst-bucket (bucket = dst >> 7)
#define NBA  256   // partition-phase blocks

__device__ inline unsigned short f2bf(float f) {      // RNE f32 -> bf16
    unsigned u = __float_as_uint(f);
    u += 0x7fff + ((u >> 16) & 1);
    return (unsigned short)(u >> 16);
}
__device__ inline float bf2f(unsigned short h) {
    return __uint_as_float(((unsigned)h) << 16);
}

// ---------- A1: per-block bucket histogram ----------
__global__ __launch_bounds__(256) void k_a1(const int* __restrict__ dst,
                                            int* __restrict__ cnt,
                                            int E, int NB, int chunk) {
    __shared__ int h[1024];
    int t = threadIdx.x;
    for (int b = t; b < NB; b += 256) h[b] = 0;
    __syncthreads();
    int e0 = blockIdx.x * chunk, e1 = min(E, e0 + chunk);
    for (int e = e0 + t; e < e1; e += 256) {
        int d = __builtin_nontemporal_load(&dst[e]);
        atomicAdd(&h[d >> 7], 1);
    }
    __syncthreads();
    for (int b = t; b < NB; b += 256) cnt[(size_t)blockIdx.x * NB + b] = h[b];
}

// ---------- A2a: per-bucket exclusive scan across blocks ----------
__global__ __launch_bounds__(NBA) void k_a2a(const int* __restrict__ cnt,
                                             int* __restrict__ offsT,
                                             int* __restrict__ total, int NB) {
    __shared__ int s[NBA];
    int t = threadIdx.x, b = blockIdx.x;
    int v = cnt[(size_t)t * NB + b];
    s[t] = v;
    __syncthreads();
    for (int off = 1; off < NBA; off <<= 1) {
        int tmp = (t >= off) ? s[t - off] : 0;
        __syncthreads();
        s[t] += tmp;
        __syncthreads();
    }
    offsT[(size_t)b * NBA + t] = s[t] - v;
    if (t == NBA - 1) total[b] = s[t];
}

// ---------- A2b: scan bucket totals -> bucket base (+sentinel) ----------
__global__ void k_a2b(const int* __restrict__ total, int* __restrict__ base, int NB) {
    __shared__ int s[1024];
    int t = threadIdx.x;
    int v = (t < NB) ? total[t] : 0;
    s[t] = v;
    __syncthreads();
    for (int off = 1; off < 1024; off <<= 1) {
        int tmp = (t >= off) ? s[t - off] : 0;
        __syncthreads();
        s[t] += tmp;
        __syncthreads();
    }
    if (t < NB) base[t] = s[t] - v;
    if (t == NB - 1) base[NB] = s[t];
}

// ---------- A3: stable partition scatter; per-block contiguous runs ----------
__global__ __launch_bounds__(256) void k_a3(const int* __restrict__ src,
                                            const int* __restrict__ dst,
                                            const int* __restrict__ offsT,
                                            const int* __restrict__ base,
                                            unsigned* __restrict__ bin,
                                            int E, int NB, int chunk) {
    __shared__ int pos[1024];
    int t = threadIdx.x, blk = blockIdx.x;
    for (int b = t; b < NB; b += 256) pos[b] = base[b] + offsT[(size_t)b * NBA + blk];
    __syncthreads();
    int e0 = blk * chunk, e1 = min(E, e0 + chunk);
    for (int e = e0 + t; e < e1; e += 256) {
        int d = __builtin_nontemporal_load(&dst[e]);
        int s = __builtin_nontemporal_load(&src[e]);
        int p = atomicAdd(&pos[d >> 7], 1);
        bin[p] = ((unsigned)s << 7) | (unsigned)(d & (TB - 1));
    }
}

// ---------- Sortb: in-bucket counting sort -> CSR + roff + dinv ----------
// One block per bucket. Counts 128 node-local bins in LDS, scans, scatters
// src indices into the bucket's contiguous csr run (16 KB, L2-local writes).
__global__ __launch_bounds__(256) void k_sortb(const unsigned* __restrict__ bin,
                                               const int* __restrict__ base,
                                               int* __restrict__ csr,
                                               int* __restrict__ roff,
                                               float* __restrict__ dinv, int N) {
    __shared__ int cnt[TB], incl[TB], pos[TB];
    int t = threadIdx.x, b = blockIdx.x;
    if (t < TB) cnt[t] = 0;
    __syncthreads();
    int j0 = base[b], j1 = base[b + 1];
    for (int j = j0 + t; j < j1; j += 256)
        atomicAdd(&cnt[bin[j] & (TB - 1)], 1);
    __syncthreads();
    if (t < TB) incl[t] = cnt[t];
    __syncthreads();
    for (int off = 1; off < TB; off <<= 1) {
        int v = (t < TB && t >= off) ? incl[t - off] : 0;
        __syncthreads();
        if (t < TB) incl[t] += v;
        __syncthreads();
    }
    if (t < TB) {
        int ex = incl[t] - cnt[t];
        pos[t] = ex;
        int node = b * TB + t;
        if (node < N) {
            roff[node] = j0 + ex;
            dinv[node] = rsqrtf((float)cnt[t] + 1.0f);  // +1 self loop
        } else if (node == N) {
            roff[N] = j0 + ex;
        }
    }
    __syncthreads();
    for (int j = j0 + t; j < j1; j += 256) {
        unsigned v = bin[j];
        int p = atomicAdd(&pos[v & (TB - 1)], 1);
        csr[j0 + p] = (int)(v >> 7);
    }
}

// ---------- GEMM1: h1b[i][c] = bf16((x[i] . W1[:,c]) * dinv[i]) ----------
#define KS  4
#define KCH (F_IN / KS)  // 128
__global__ __launch_bounds__(256) void k_gemm1(const float* __restrict__ x,
                                               const float* __restrict__ W1,
                                               const float* __restrict__ dinv,
                                               unsigned short* __restrict__ h1b, int n) {
    __shared__ float wlds[F_IN * HID];      // 32 KB
    __shared__ float red[3 * 64 * HID];     // 12 KB
    int t = threadIdx.x;
    int wid = t >> 6;
    int lane = t & 63;

    for (int i = t * 4; i < F_IN * HID; i += 256 * 4)
        *(float4*)&wlds[i] = *(const float4*)&W1[i];
    __syncthreads();

    int row = blockIdx.x * 64 + lane;
    int rclamp = (row < n) ? row : (n - 1);
    const float* xp = x + (size_t)rclamp * F_IN + wid * KCH;
    const float* wp = &wlds[wid * KCH * HID];

    float acc[HID];
#pragma unroll
    for (int c = 0; c < HID; c++) acc[c] = 0.f;

#pragma unroll 8
    for (int k4 = 0; k4 < KCH / 4; k4++) {
        float4 xv = *(const float4*)&xp[k4 * 4];
#pragma unroll
        for (int kk = 0; kk < 4; kk++) {
            float xs = ((const float*)&xv)[kk];
            const float4* wr = (const float4*)&wp[(k4 * 4 + kk) * HID];
#pragma unroll
            for (int cg = 0; cg < 4; cg++) {
                float4 wv = wr[cg];
                acc[cg * 4 + 0] = fmaf(xs, wv.x, acc[cg * 4 + 0]);
                acc[cg * 4 + 1] = fmaf(xs, wv.y, acc[cg * 4 + 1]);
                acc[cg * 4 + 2] = fmaf(xs, wv.z, acc[cg * 4 + 2]);
                acc[cg * 4 + 3] = fmaf(xs, wv.w, acc[cg * 4 + 3]);
            }
        }
    }

    if (wid > 0) {
        float* r = &red[((wid - 1) * 64 + lane) * HID];
#pragma unroll
        for (int cg = 0; cg < 4; cg++)
            *(float4*)&r[cg * 4] = make_float4(acc[cg * 4], acc[cg * 4 + 1],
                                               acc[cg * 4 + 2], acc[cg * 4 + 3]);
    }
    __syncthreads();
    if (wid == 0 && row < n) {
        float dv = dinv[row];
        float o[HID];
#pragma unroll
        for (int cg = 0; cg < 4; cg++) {
            float4 p0 = *(float4*)&red[(0 * 64 + lane) * HID + cg * 4];
            float4 p1 = *(float4*)&red[(1 * 64 + lane) * HID + cg * 4];
            float4 p2 = *(float4*)&red[(2 * 64 + lane) * HID + cg * 4];
            o[cg * 4 + 0] = (acc[cg * 4 + 0] + p0.x + p1.x + p2.x) * dv;
            o[cg * 4 + 1] = (acc[cg * 4 + 1] + p0.y + p1.y + p2.y) * dv;
            o[cg * 4 + 2] = (acc[cg * 4 + 2] + p0.z + p1.z + p2.z) * dv;
            o[cg * 4 + 3] = (acc[cg * 4 + 3] + p0.w + p1.w + p2.w) * dv;
        }
        unsigned up[8];
#pragma unroll
        for (int i = 0; i < 8; i++)
            up[i] = (unsigned)f2bf(o[2 * i]) | ((unsigned)f2bf(o[2 * i + 1]) << 16);
        unsigned* pdst = (unsigned*)(h1b + (size_t)row * HID);
        *(uint4*)pdst = make_uint4(up[0], up[1], up[2], up[3]);
        *(uint4*)(pdst + 4) = make_uint4(up[4], up[5], up[6], up[7]);
    }
}

// ---------- Agg: wave-per-node CSR gather from L2-resident bf16 h1 ----------
// z[d][c] = bf16( relu(dinv*(sum_{s->d} h1[s][c] + h1[d][c]) + b1[c]) * dinv )
__global__ __launch_bounds__(256) void k_agg(const unsigned short* __restrict__ h1b,
                                             const int* __restrict__ csr,
                                             const int* __restrict__ roff,
                                             const float* __restrict__ dinv,
                                             const float* __restrict__ b1,
                                             unsigned short* __restrict__ zb, int n) {
    int lane = threadIdx.x & 63;
    int node = (blockIdx.x * blockDim.x + threadIdx.x) >> 6;  // one wave per node
    if (node >= n) return;
    int c = lane & 15, sub = lane >> 4;
    int s0 = roff[node], s1 = roff[node + 1];
    float sum = 0.f;
    for (int j = s0 + sub; j < s1; j += 4)
        sum += bf2f(h1b[(size_t)csr[j] * HID + c]);
    sum += __shfl_xor(sum, 16);
    sum += __shfl_xor(sum, 32);
    sum += bf2f(h1b[(size_t)node * HID + c]);  // self loop
    float dv = dinv[node];
    float pre = dv * sum + b1[c];
    if (lane < 16) zb[(size_t)node * HID + c] = f2bf(fmaxf(pre, 0.f) * dv);
}

// ---------- Out: layer-2 gather (rows %20 only) + matvec + log_softmax ----------
__global__ void k_out(const unsigned short* __restrict__ zb,
                      const int* __restrict__ csr, const int* __restrict__ roff,
                      const float* __restrict__ dinv, const float* __restrict__ W2,
                      const float* __restrict__ b2, float* __restrict__ out, int nOut) {
    int lane = threadIdx.x & 63;
    int wv = (blockIdx.x * blockDim.x + threadIdx.x) >> 6;  // one wave per out row
    if (wv >= nOut) return;
    int node = wv * OUT_STRIDE;
    int c = lane & 15, sub = lane >> 4;
    int s0 = roff[node], s1 = roff[node + 1];
    float sum = 0.f;
    for (int j = s0 + sub; j < s1; j += 4)
        sum += bf2f(zb[(size_t)csr[j] * HID + c]);
    sum += __shfl_xor(sum, 16);
    sum += __shfl_xor(sum, 32);
    sum += bf2f(zb[(size_t)node * HID + c]);  // self loop
    float a = dinv[node] * sum;

    int jj = lane < NCLS ? lane : 0;
    float v = 0.f;
#pragma unroll
    for (int cc = 0; cc < 16; cc++) {
        float ac = __shfl(a, cc);  // lane cc holds column cc
        v = fmaf(ac, W2[cc * NCLS + jj], v);
    }
    v += b2[jj];

    float vm = lane < NCLS ? v : -INFINITY;
    for (int off = 1; off < 64; off <<= 1) vm = fmaxf(vm, __shfl_xor(vm, off));
    float ex = lane < NCLS ? expf(v - vm) : 0.f;
    float se = ex;
    for (int off = 1; off < 64; off <<= 1) se += __shfl_xor(se, off);
    float ls = logf(se);
    if (lane < NCLS) out[(size_t)wv * NCLS + lane] = v - vm - ls;
}

// ---------------- host launcher ----------------
extern "C" void kernel_launch(void* const* d_in, const int* in_sizes, int n_in,
                              void* d_out, int out_size, void* d_ws, size_t ws_size,
                              hipStream_t stream) {
    const int E = in_sizes[0] / 2;
    const int N = in_sizes[1] / F_IN;
    const int nOut = (N + OUT_STRIDE - 1) / OUT_STRIDE;
    const int NB = (N + TB - 1) / TB;                 // 782
    const int chunk = (E + NBA - 1) / NBA;

    const int* src = (const int*)d_in[0];
    const int* dst = src + E;
    const float* x  = (const float*)d_in[1];
    const float* W1 = (const float*)d_in[2];
    const float* b1 = (const float*)d_in[3];
    const float* W2 = (const float*)d_in[4];
    const float* b2 = (const float*)d_in[5];
    float* out = (float*)d_out;

    uint8_t* w = (uint8_t*)d_ws;
    size_t off = 0;
    auto carve = [&](size_t bytes) {
        void* p = w + off;
        off += (bytes + 15) & ~(size_t)15;
        return p;
    };
    float*          dinv  = (float*)carve((size_t)N * 4);
    unsigned*       bin   = (unsigned*)carve((size_t)E * 4);
    int*            cnt   = (int*)carve((size_t)NBA * NB * 4);
    int*            offsT = (int*)carve((size_t)NB * NBA * 4);
    int*            total = (int*)carve((size_t)NB * 4);
    int*            base  = (int*)carve((size_t)(NB + 1) * 4);
    int*            csr   = (int*)carve((size_t)E * 4);
    int*            roff  = (int*)carve((size_t)(N + 1) * 4);
    unsigned short* h1b   = (unsigned short*)carve((size_t)N * HID * 2);
    unsigned short* zb    = (unsigned short*)carve((size_t)N * HID * 2);
    (void)ws_size; (void)n_in; (void)out_size;

    k_a1  <<<NBA, 256, 0, stream>>>(dst, cnt, E, NB, chunk);
    k_a2a <<<NB, NBA, 0, stream>>>(cnt, offsT, total, NB);
    k_a2b <<<1, 1024, 0, stream>>>(total, base, NB);
    k_a3  <<<NBA, 256, 0, stream>>>(src, dst, offsT, base, bin, E, NB, chunk);
    k_sortb<<<NB, 256, 0, stream>>>(bin, base, csr, roff, dinv, N);
    k_gemm1<<<(N + 63) / 64, 256, 0, stream>>>(x, W1, dinv, h1b, N);
    k_agg <<<(N * 64 + 255) / 256, 256, 0, stream>>>(h1b, csr, roff, dinv, b1, zb, N);
    k_out <<<(nOut * 64 + 255) / 256, 256, 0, stream>>>(zb, csr, roff, dinv, W2, b2, out, nOut);
}

// Round 9
// 220.921 us; speedup vs baseline: 2.6872x; 1.1315x over previous
//
#include <hip/hip_runtime.h>
#include <cstdint>
#include <math.h>

#define F_IN 512
#define HID  16
#define NCLS 40
#define OUT_STRIDE 20
#define TB   128   // nodes per dst-bucket (bucket = dst >> 7)
#define NBA  256   // partition-phase blocks

typedef __attribute__((ext_vector_type(8))) short short8;
typedef __attribute__((ext_vector_type(4))) float f32x4;

__device__ inline unsigned short f2bf(float f) {      // RNE f32 -> bf16
    unsigned u = __float_as_uint(f);
    u += 0x7fff + ((u >> 16) & 1);
    return (unsigned short)(u >> 16);
}
__device__ inline float bf2f(unsigned short h) {
    return __uint_as_float(((unsigned)h) << 16);
}

// ---------- A1: per-block bucket histogram ----------
__global__ __launch_bounds__(256) void k_a1(const int* __restrict__ dst,
                                            int* __restrict__ cnt,
                                            int E, int NB, int chunk) {
    __shared__ int h[1024];
    int t = threadIdx.x;
    for (int b = t; b < NB; b += 256) h[b] = 0;
    __syncthreads();
    int e0 = blockIdx.x * chunk, e1 = min(E, e0 + chunk);
    for (int e = e0 + t; e < e1; e += 256) {
        int d = __builtin_nontemporal_load(&dst[e]);
        atomicAdd(&h[d >> 7], 1);
    }
    __syncthreads();
    for (int b = t; b < NB; b += 256) cnt[(size_t)blockIdx.x * NB + b] = h[b];
}

// ---------- A2a: per-bucket exclusive scan across blocks ----------
__global__ __launch_bounds__(NBA) void k_a2a(const int* __restrict__ cnt,
                                             int* __restrict__ offsT,
                                             int* __restrict__ total, int NB) {
    __shared__ int s[NBA];
    int t = threadIdx.x, b = blockIdx.x;
    int v = cnt[(size_t)t * NB + b];
    s[t] = v;
    __syncthreads();
    for (int off = 1; off < NBA; off <<= 1) {
        int tmp = (t >= off) ? s[t - off] : 0;
        __syncthreads();
        s[t] += tmp;
        __syncthreads();
    }
    offsT[(size_t)b * NBA + t] = s[t] - v;
    if (t == NBA - 1) total[b] = s[t];
}

// ---------- A2b: scan bucket totals -> bucket base (+sentinel) ----------
__global__ void k_a2b(const int* __restrict__ total, int* __restrict__ base, int NB) {
    __shared__ int s[1024];
    int t = threadIdx.x;
    int v = (t < NB) ? total[t] : 0;
    s[t] = v;
    __syncthreads();
    for (int off = 1; off < 1024; off <<= 1) {
        int tmp = (t >= off) ? s[t - off] : 0;
        __syncthreads();
        s[t] += tmp;
        __syncthreads();
    }
    if (t < NB) base[t] = s[t] - v;
    if (t == NB - 1) base[NB] = s[t];
}

// ---------- A3: stable partition scatter; per-block contiguous runs ----------
__global__ __launch_bounds__(256) void k_a3(const int* __restrict__ src,
                                            const int* __restrict__ dst,
                                            const int* __restrict__ offsT,
                                            const int* __restrict__ base,
                                            unsigned* __restrict__ bin,
                                            int E, int NB, int chunk) {
    __shared__ int pos[1024];
    int t = threadIdx.x, blk = blockIdx.x;
    for (int b = t; b < NB; b += 256) pos[b] = base[b] + offsT[(size_t)b * NBA + blk];
    __syncthreads();
    int e0 = blk * chunk, e1 = min(E, e0 + chunk);
    for (int e = e0 + t; e < e1; e += 256) {
        int d = __builtin_nontemporal_load(&dst[e]);
        int s = __builtin_nontemporal_load(&src[e]);
        int p = atomicAdd(&pos[d >> 7], 1);
        bin[p] = ((unsigned)s << 7) | (unsigned)(d & (TB - 1));
    }
}

// ---------- Sortb: in-bucket counting sort -> CSR + roff + dinv ----------
__global__ __launch_bounds__(256) void k_sortb(const unsigned* __restrict__ bin,
                                               const int* __restrict__ base,
                                               int* __restrict__ csr,
                                               int* __restrict__ roff,
                                               float* __restrict__ dinv, int N) {
    __shared__ int cnt[TB], incl[TB], pos[TB];
    int t = threadIdx.x, b = blockIdx.x;
    if (t < TB) cnt[t] = 0;
    __syncthreads();
    int j0 = base[b], j1 = base[b + 1];
    for (int j = j0 + t; j < j1; j += 256)
        atomicAdd(&cnt[bin[j] & (TB - 1)], 1);
    __syncthreads();
    if (t < TB) incl[t] = cnt[t];
    __syncthreads();
    for (int off = 1; off < TB; off <<= 1) {
        int v = (t < TB && t >= off) ? incl[t - off] : 0;
        __syncthreads();
        if (t < TB) incl[t] += v;
        __syncthreads();
    }
    if (t < TB) {
        int ex = incl[t] - cnt[t];
        pos[t] = ex;
        int node = b * TB + t;
        if (node < N) {
            roff[node] = j0 + ex;
            dinv[node] = rsqrtf((float)cnt[t] + 1.0f);  // +1 self loop
        } else if (node == N) {
            roff[N] = j0 + ex;
        }
    }
    __syncthreads();
    for (int j = j0 + t; j < j1; j += 256) {
        unsigned v = bin[j];
        int p = atomicAdd(&pos[v & (TB - 1)], 1);
        csr[j0 + p] = (int)(v >> 7);
    }
}

// ---------- GEMM1 via MFMA: h1b[i][c] = bf16((x[i] . W1[:,c]) * dinv[i]) ----
// Block = 4 waves x 64 rows = 256 rows. Per wave: 4 row-tiles of 16, full
// K = 512 as 16 k-steps of 32. B (W1) prepacked in LDS as per-lane MFMA
// fragments: one ds_read_b128 per k-step, reused across 4 row-tiles.
// A: lane loads 8 f32 of row (lane&15) at k = kstep*32 + (lane>>4)*8
// (two coalesced float4 loads), packs to bf16x8. C layout: col = lane&15,
// row = (lane>>4)*4 + reg (guide §3, m89-verified).
__global__ __launch_bounds__(256) void k_gemm1m(const float* __restrict__ x,
                                                const float* __restrict__ W1,
                                                const float* __restrict__ dinv,
                                                unsigned short* __restrict__ h1b, int n) {
    __shared__ uint4 bfrag[16][64];   // 16 KB: [kstep][lane] = 8 bf16
    int t = threadIdx.x;
    int wid = t >> 6, lane = t & 63;

    // prepack W1 -> B fragments (each W1 element read exactly once per block)
    for (int idx = t; idx < 16 * 64; idx += 256) {
        int kstep = idx >> 6, ln = idx & 63;
        int col = ln & 15, k0 = kstep * 32 + (ln >> 4) * 8;
        unsigned up[4];
#pragma unroll
        for (int i = 0; i < 4; i++) {
            float a = W1[(k0 + 2 * i) * HID + col];
            float b = W1[(k0 + 2 * i + 1) * HID + col];
            up[i] = (unsigned)f2bf(a) | ((unsigned)f2bf(b) << 16);
        }
        bfrag[kstep][ln] = make_uint4(up[0], up[1], up[2], up[3]);
    }
    __syncthreads();

    int rows0 = blockIdx.x * 256 + wid * 64;   // this wave's 64 rows
    int arow = lane & 15, kgrp = lane >> 4;

    const float* xr[4];
#pragma unroll
    for (int rt = 0; rt < 4; rt++) {
        int r = rows0 + rt * 16 + arow;
        if (r >= n) r = n - 1;                 // clamp loads; stores guarded
        xr[rt] = x + (size_t)r * F_IN + kgrp * 8;
    }

    f32x4 acc[4];
#pragma unroll
    for (int rt = 0; rt < 4; rt++) acc[rt] = (f32x4){0.f, 0.f, 0.f, 0.f};

#pragma unroll 4
    for (int kstep = 0; kstep < 16; kstep++) {
        uint4 braw = bfrag[kstep][lane];
        short8 b;
        *(uint4*)&b = braw;
#pragma unroll
        for (int rt = 0; rt < 4; rt++) {
            float4 lo = *(const float4*)(xr[rt] + kstep * 32);
            float4 hi = *(const float4*)(xr[rt] + kstep * 32 + 4);
            short8 a;
            a[0] = (short)f2bf(lo.x); a[1] = (short)f2bf(lo.y);
            a[2] = (short)f2bf(lo.z); a[3] = (short)f2bf(lo.w);
            a[4] = (short)f2bf(hi.x); a[5] = (short)f2bf(hi.y);
            a[6] = (short)f2bf(hi.z); a[7] = (short)f2bf(hi.w);
            acc[rt] = __builtin_amdgcn_mfma_f32_16x16x32_bf16(a, b, acc[rt], 0, 0, 0);
        }
    }

    // epilogue: C[row'][col], row' = (lane>>4)*4 + r, col = lane&15
    int col = lane & 15, rbase = (lane >> 4) * 4;
#pragma unroll
    for (int rt = 0; rt < 4; rt++) {
#pragma unroll
        for (int r = 0; r < 4; r++) {
            int row = rows0 + rt * 16 + rbase + r;
            if (row < n)
                h1b[(size_t)row * HID + col] = f2bf(acc[rt][r] * dinv[row]);
        }
    }
}

// ---------- Agg: wave-per-node CSR gather from L2-resident bf16 h1 ----------
__global__ __launch_bounds__(256) void k_agg(const unsigned short* __restrict__ h1b,
                                             const int* __restrict__ csr,
                                             const int* __restrict__ roff,
                                             const float* __restrict__ dinv,
                                             const float* __restrict__ b1,
                                             unsigned short* __restrict__ zb, int n) {
    int lane = threadIdx.x & 63;
    int node = (blockIdx.x * blockDim.x + threadIdx.x) >> 6;  // one wave per node
    if (node >= n) return;
    int c = lane & 15, sub = lane >> 4;
    int s0 = roff[node], s1 = roff[node + 1];
    float sum = 0.f;
    for (int j = s0 + sub; j < s1; j += 4)
        sum += bf2f(h1b[(size_t)csr[j] * HID + c]);
    sum += __shfl_xor(sum, 16);
    sum += __shfl_xor(sum, 32);
    sum += bf2f(h1b[(size_t)node * HID + c]);  // self loop
    float dv = dinv[node];
    float pre = dv * sum + b1[c];
    if (lane < 16) zb[(size_t)node * HID + c] = f2bf(fmaxf(pre, 0.f) * dv);
}

// ---------- Out: layer-2 gather (rows %20 only) + matvec + log_softmax ----------
__global__ void k_out(const unsigned short* __restrict__ zb,
                      const int* __restrict__ csr, const int* __restrict__ roff,
                      const float* __restrict__ dinv, const float* __restrict__ W2,
                      const float* __restrict__ b2, float* __restrict__ out, int nOut) {
    int lane = threadIdx.x & 63;
    int wv = (blockIdx.x * blockDim.x + threadIdx.x) >> 6;  // one wave per out row
    if (wv >= nOut) return;
    int node = wv * OUT_STRIDE;
    int c = lane & 15, sub = lane >> 4;
    int s0 = roff[node], s1 = roff[node + 1];
    float sum = 0.f;
    for (int j = s0 + sub; j < s1; j += 4)
        sum += bf2f(zb[(size_t)csr[j] * HID + c]);
    sum += __shfl_xor(sum, 16);
    sum += __shfl_xor(sum, 32);
    sum += bf2f(zb[(size_t)node * HID + c]);  // self loop
    float a = dinv[node] * sum;

    int jj = lane < NCLS ? lane : 0;
    float v = 0.f;
#pragma unroll
    for (int cc = 0; cc < 16; cc++) {
        float ac = __shfl(a, cc);  // lane cc holds column cc
        v = fmaf(ac, W2[cc * NCLS + jj], v);
    }
    v += b2[jj];

    float vm = lane < NCLS ? v : -INFINITY;
    for (int off = 1; off < 64; off <<= 1) vm = fmaxf(vm, __shfl_xor(vm, off));
    float ex = lane < NCLS ? expf(v - vm) : 0.f;
    float se = ex;
    for (int off = 1; off < 64; off <<= 1) se += __shfl_xor(se, off);
    float ls = logf(se);
    if (lane < NCLS) out[(size_t)wv * NCLS + lane] = v - vm - ls;
}

// ---------------- host launcher ----------------
extern "C" void kernel_launch(void* const* d_in, const int* in_sizes, int n_in,
                              void* d_out, int out_size, void* d_ws, size_t ws_size,
                              hipStream_t stream) {
    const int E = in_sizes[0] / 2;
    const int N = in_sizes[1] / F_IN;
    const int nOut = (N + OUT_STRIDE - 1) / OUT_STRIDE;
    const int NB = (N + TB - 1) / TB;                 // 782
    const int chunk = (E + NBA - 1) / NBA;

    const int* src = (const int*)d_in[0];
    const int* dst = src + E;
    const float* x  = (const float*)d_in[1];
    const float* W1 = (const float*)d_in[2];
    const float* b1 = (const float*)d_in[3];
    const float* W2 = (const float*)d_in[4];
    const float* b2 = (const float*)d_in[5];
    float* out = (float*)d_out;

    uint8_t* w = (uint8_t*)d_ws;
    size_t off = 0;
    auto carve = [&](size_t bytes) {
        void* p = w + off;
        off += (bytes + 15) & ~(size_t)15;
        return p;
    };
    float*          dinv  = (float*)carve((size_t)N * 4);
    unsigned*       bin   = (unsigned*)carve((size_t)E * 4);
    int*            cnt   = (int*)carve((size_t)NBA * NB * 4);
    int*            offsT = (int*)carve((size_t)NB * NBA * 4);
    int*            total = (int*)carve((size_t)NB * 4);
    int*            base  = (int*)carve((size_t)(NB + 1) * 4);
    int*            csr   = (int*)carve((size_t)E * 4);
    int*            roff  = (int*)carve((size_t)(N + 1) * 4);
    unsigned short* h1b   = (unsigned short*)carve((size_t)N * HID * 2);
    unsigned short* zb    = (unsigned short*)carve((size_t)N * HID * 2);
    (void)ws_size; (void)n_in; (void)out_size;

    k_a1   <<<NBA, 256, 0, stream>>>(dst, cnt, E, NB, chunk);
    k_a2a  <<<NB, NBA, 0, stream>>>(cnt, offsT, total, NB);
    k_a2b  <<<1, 1024, 0, stream>>>(total, base, NB);
    k_a3   <<<NBA, 256, 0, stream>>>(src, dst, offsT, base, bin, E, NB, chunk);
    k_sortb<<<NB, 256, 0, stream>>>(bin, base, csr, roff, dinv, N);
    k_gemm1m<<<(N + 255) / 256, 256, 0, stream>>>(x, W1, dinv, h1b, N);
    k_agg  <<<(N * 64 + 255) / 256, 256, 0, stream>>>(h1b, csr, roff, dinv, b1, zb, N);
    k_out  <<<(nOut * 64 + 255) / 256, 256, 0, stream>>>(zb, csr, roff, dinv, W2, b2, out, nOut);
}

// Round 10
// 201.387 us; speedup vs baseline: 2.9479x; 1.0970x over previous
//
#include <hip/hip_runtime.h>
#include <cstdint>
#include <math.h>

#define F_IN 512
#define HID  16
#define NCLS 40
#define OUT_STRIDE 20
#define TB   128   // nodes per dst-bucket (bucket = dst >> 7)
#define NBA  512   // partition-phase blocks

typedef __attribute__((ext_vector_type(8))) short short8;
typedef __attribute__((ext_vector_type(4))) float f32x4;

__device__ inline unsigned short f2bf(float f) {      // RNE f32 -> bf16
    unsigned u = __float_as_uint(f);
    u += 0x7fff + ((u >> 16) & 1);
    return (unsigned short)(u >> 16);
}
__device__ inline float bf2f(unsigned short h) {
    return __uint_as_float(((unsigned)h) << 16);
}

// ---------- A1: per-block bucket histogram ----------
__global__ __launch_bounds__(256) void k_a1(const int* __restrict__ dst,
                                            int* __restrict__ cnt,
                                            int E, int NB, int chunk) {
    __shared__ int h[1024];
    int t = threadIdx.x;
    for (int b = t; b < NB; b += 256) h[b] = 0;
    __syncthreads();
    int e0 = blockIdx.x * chunk, e1 = min(E, e0 + chunk);
    for (int e = e0 + t; e < e1; e += 256) {
        int d = __builtin_nontemporal_load(&dst[e]);
        atomicAdd(&h[d >> 7], 1);
    }
    __syncthreads();
    for (int b = t; b < NB; b += 256) cnt[(size_t)blockIdx.x * NB + b] = h[b];
}

// ---------- A2a: per-bucket exclusive scan across blocks ----------
__global__ __launch_bounds__(NBA) void k_a2a(const int* __restrict__ cnt,
                                             int* __restrict__ offsT,
                                             int* __restrict__ total, int NB) {
    __shared__ int s[NBA];
    int t = threadIdx.x, b = blockIdx.x;
    int v = cnt[(size_t)t * NB + b];
    s[t] = v;
    __syncthreads();
    for (int off = 1; off < NBA; off <<= 1) {
        int tmp = (t >= off) ? s[t - off] : 0;
        __syncthreads();
        s[t] += tmp;
        __syncthreads();
    }
    offsT[(size_t)b * NBA + t] = s[t] - v;
    if (t == NBA - 1) total[b] = s[t];
}

// ---------- A2b: scan bucket totals -> bucket base (+sentinel) ----------
__global__ void k_a2b(const int* __restrict__ total, int* __restrict__ base, int NB) {
    __shared__ int s[1024];
    int t = threadIdx.x;
    int v = (t < NB) ? total[t] : 0;
    s[t] = v;
    __syncthreads();
    for (int off = 1; off < 1024; off <<= 1) {
        int tmp = (t >= off) ? s[t - off] : 0;
        __syncthreads();
        s[t] += tmp;
        __syncthreads();
    }
    if (t < NB) base[t] = s[t] - v;
    if (t == NB - 1) base[NB] = s[t];
}

// ---------- A3: stable partition scatter; per-block contiguous runs ----------
__global__ __launch_bounds__(256) void k_a3(const int* __restrict__ src,
                                            const int* __restrict__ dst,
                                            const int* __restrict__ offsT,
                                            const int* __restrict__ base,
                                            unsigned* __restrict__ bin,
                                            int E, int NB, int chunk) {
    __shared__ int pos[1024];
    int t = threadIdx.x, blk = blockIdx.x;
    for (int b = t; b < NB; b += 256) pos[b] = base[b] + offsT[(size_t)b * NBA + blk];
    __syncthreads();
    int e0 = blk * chunk, e1 = min(E, e0 + chunk);
    for (int e = e0 + t; e < e1; e += 256) {
        int d = __builtin_nontemporal_load(&dst[e]);
        int s = __builtin_nontemporal_load(&src[e]);
        int p = atomicAdd(&pos[d >> 7], 1);
        bin[p] = ((unsigned)s << 7) | (unsigned)(d & (TB - 1));
    }
}

// ---------- Sortb: in-bucket counting sort -> CSR + roff + dinv ----------
__global__ __launch_bounds__(256) void k_sortb(const unsigned* __restrict__ bin,
                                               const int* __restrict__ base,
                                               int* __restrict__ csr,
                                               int* __restrict__ roff,
                                               float* __restrict__ dinv, int N) {
    __shared__ int cnt[TB], incl[TB], pos[TB];
    int t = threadIdx.x, b = blockIdx.x;
    if (t < TB) cnt[t] = 0;
    __syncthreads();
    int j0 = base[b], j1 = base[b + 1];
    for (int j = j0 + t; j < j1; j += 256)
        atomicAdd(&cnt[bin[j] & (TB - 1)], 1);
    __syncthreads();
    if (t < TB) incl[t] = cnt[t];
    __syncthreads();
    for (int off = 1; off < TB; off <<= 1) {
        int v = (t < TB && t >= off) ? incl[t - off] : 0;
        __syncthreads();
        if (t < TB) incl[t] += v;
        __syncthreads();
    }
    if (t < TB) {
        int ex = incl[t] - cnt[t];
        pos[t] = ex;
        int node = b * TB + t;
        if (node < N) {
            roff[node] = j0 + ex;
            dinv[node] = rsqrtf((float)cnt[t] + 1.0f);  // +1 self loop
        } else if (node == N) {
            roff[N] = j0 + ex;
        }
    }
    __syncthreads();
    for (int j = j0 + t; j < j1; j += 256) {
        unsigned v = bin[j];
        int p = atomicAdd(&pos[v & (TB - 1)], 1);
        csr[j0 + p] = (int)(v >> 7);
    }
}

// ---------- Prew: prepack W1 into MFMA B-fragments (global, L2-hot) ----------
// bfragg[kstep][lane] = 8 bf16 of W1[k0..k0+7][col], col=lane&15,
// k0 = kstep*32 + (lane>>4)*8  (layout verified by R9's passing check)
__global__ void k_prew(const float* __restrict__ W1, uint4* __restrict__ bfragg) {
    int idx = blockIdx.x * blockDim.x + threadIdx.x;
    if (idx >= 16 * 64) return;
    int kstep = idx >> 6, ln = idx & 63;
    int col = ln & 15, k0 = kstep * 32 + (ln >> 4) * 8;
    unsigned up[4];
#pragma unroll
    for (int i = 0; i < 4; i++) {
        float a = W1[(k0 + 2 * i) * HID + col];
        float b = W1[(k0 + 2 * i + 1) * HID + col];
        up[i] = (unsigned)f2bf(a) | ((unsigned)f2bf(b) << 16);
    }
    bfragg[idx] = make_uint4(up[0], up[1], up[2], up[3]);
}

// ---------- GEMM1 via MFMA, 1 wave / 64 rows, no LDS ----------
__global__ __launch_bounds__(64) void k_gemm1m(const float* __restrict__ x,
                                               const uint4* __restrict__ bfragg,
                                               const float* __restrict__ dinv,
                                               unsigned short* __restrict__ h1b, int n) {
    int lane = threadIdx.x;
    int rows0 = blockIdx.x * 64;
    int arow = lane & 15, kgrp = lane >> 4;

    const float* xr[4];
#pragma unroll
    for (int rt = 0; rt < 4; rt++) {
        int r = rows0 + rt * 16 + arow;
        if (r >= n) r = n - 1;                 // clamp loads; stores guarded
        xr[rt] = x + (size_t)r * F_IN + kgrp * 8;
    }

    f32x4 acc[4];
#pragma unroll
    for (int rt = 0; rt < 4; rt++) acc[rt] = (f32x4){0.f, 0.f, 0.f, 0.f};

#pragma unroll 4
    for (int kstep = 0; kstep < 16; kstep++) {
        uint4 braw = bfragg[kstep * 64 + lane];   // L2-resident broadcast
        short8 b;
        *(uint4*)&b = braw;
#pragma unroll
        for (int rt = 0; rt < 4; rt++) {
            float4 lo = *(const float4*)(xr[rt] + kstep * 32);
            float4 hi = *(const float4*)(xr[rt] + kstep * 32 + 4);
            short8 a;
            a[0] = (short)f2bf(lo.x); a[1] = (short)f2bf(lo.y);
            a[2] = (short)f2bf(lo.z); a[3] = (short)f2bf(lo.w);
            a[4] = (short)f2bf(hi.x); a[5] = (short)f2bf(hi.y);
            a[6] = (short)f2bf(hi.z); a[7] = (short)f2bf(hi.w);
            acc[rt] = __builtin_amdgcn_mfma_f32_16x16x32_bf16(a, b, acc[rt], 0, 0, 0);
        }
    }

    // C layout: row' = (lane>>4)*4 + r, col = lane&15
    int col = lane & 15, rbase = (lane >> 4) * 4;
#pragma unroll
    for (int rt = 0; rt < 4; rt++) {
#pragma unroll
        for (int r = 0; r < 4; r++) {
            int row = rows0 + rt * 16 + rbase + r;
            if (row < n)
                h1b[(size_t)row * HID + col] = f2bf(acc[rt][r] * dinv[row]);
        }
    }
}

// ---------- Agg: wave-per-node, 8 subgroups x 8 lanes, uint (2-col) loads ----
// z[d] = bf16( relu(dinv*(sum_{s->d} h1[s] + h1[d]) + b1) * dinv )
__global__ __launch_bounds__(256) void k_agg(const unsigned* __restrict__ h1u,
                                             const int* __restrict__ csr,
                                             const int* __restrict__ roff,
                                             const float* __restrict__ dinv,
                                             const float* __restrict__ b1,
                                             unsigned* __restrict__ zu, int n) {
    int lane = threadIdx.x & 63;
    int node = (blockIdx.x * blockDim.x + threadIdx.x) >> 6;  // one wave per node
    if (node >= n) return;
    int cp = lane & 7;        // col-pair: cols 2cp, 2cp+1
    int sub = lane >> 3;      // 8 subgroups -> 8 edges in flight
    int s0 = roff[node], s1 = roff[node + 1];
    float sa = 0.f, sb = 0.f;
    for (int j = s0 + sub; j < s1; j += 8) {
        unsigned u = h1u[(size_t)csr[j] * 8 + cp];
        sa += bf2f((unsigned short)(u & 0xffff));
        sb += bf2f((unsigned short)(u >> 16));
    }
    sa += __shfl_xor(sa, 8);  sb += __shfl_xor(sb, 8);
    sa += __shfl_xor(sa, 16); sb += __shfl_xor(sb, 16);
    sa += __shfl_xor(sa, 32); sb += __shfl_xor(sb, 32);
    unsigned us = h1u[(size_t)node * 8 + cp];                 // self loop
    sa += bf2f((unsigned short)(us & 0xffff));
    sb += bf2f((unsigned short)(us >> 16));
    float dv = dinv[node];
    float pa = dv * sa + b1[2 * cp];
    float pb = dv * sb + b1[2 * cp + 1];
    if (lane < 8) {
        unsigned short za = f2bf(fmaxf(pa, 0.f) * dv);
        unsigned short zbv = f2bf(fmaxf(pb, 0.f) * dv);
        zu[(size_t)node * 8 + cp] = (unsigned)za | ((unsigned)zbv << 16);
    }
}

// ---------- Out: layer-2 gather (rows %20 only) + matvec + log_softmax ----------
__global__ void k_out(const unsigned short* __restrict__ zb,
                      const int* __restrict__ csr, const int* __restrict__ roff,
                      const float* __restrict__ dinv, const float* __restrict__ W2,
                      const float* __restrict__ b2, float* __restrict__ out, int nOut) {
    int lane = threadIdx.x & 63;
    int wv = (blockIdx.x * blockDim.x + threadIdx.x) >> 6;  // one wave per out row
    if (wv >= nOut) return;
    int node = wv * OUT_STRIDE;
    int c = lane & 15, sub = lane >> 4;
    int s0 = roff[node], s1 = roff[node + 1];
    float sum = 0.f;
    for (int j = s0 + sub; j < s1; j += 4)
        sum += bf2f(zb[(size_t)csr[j] * HID + c]);
    sum += __shfl_xor(sum, 16);
    sum += __shfl_xor(sum, 32);
    sum += bf2f(zb[(size_t)node * HID + c]);  // self loop
    float a = dinv[node] * sum;

    int jj = lane < NCLS ? lane : 0;
    float v = 0.f;
#pragma unroll
    for (int cc = 0; cc < 16; cc++) {
        float ac = __shfl(a, cc);  // lane cc holds column cc
        v = fmaf(ac, W2[cc * NCLS + jj], v);
    }
    v += b2[jj];

    float vm = lane < NCLS ? v : -INFINITY;
    for (int off = 1; off < 64; off <<= 1) vm = fmaxf(vm, __shfl_xor(vm, off));
    float ex = lane < NCLS ? expf(v - vm) : 0.f;
    float se = ex;
    for (int off = 1; off < 64; off <<= 1) se += __shfl_xor(se, off);
    float ls = logf(se);
    if (lane < NCLS) out[(size_t)wv * NCLS + lane] = v - vm - ls;
}

// ---------------- host launcher ----------------
extern "C" void kernel_launch(void* const* d_in, const int* in_sizes, int n_in,
                              void* d_out, int out_size, void* d_ws, size_t ws_size,
                              hipStream_t stream) {
    const int E = in_sizes[0] / 2;
    const int N = in_sizes[1] / F_IN;
    const int nOut = (N + OUT_STRIDE - 1) / OUT_STRIDE;
    const int NB = (N + TB - 1) / TB;                 // 782
    const int chunk = (E + NBA - 1) / NBA;

    const int* src = (const int*)d_in[0];
    const int* dst = src + E;
    const float* x  = (const float*)d_in[1];
    const float* W1 = (const float*)d_in[2];
    const float* b1 = (const float*)d_in[3];
    const float* W2 = (const float*)d_in[4];
    const float* b2 = (const float*)d_in[5];
    float* out = (float*)d_out;

    uint8_t* w = (uint8_t*)d_ws;
    size_t off = 0;
    auto carve = [&](size_t bytes) {
        void* p = w + off;
        off += (bytes + 15) & ~(size_t)15;
        return p;
    };
    float*          dinv  = (float*)carve((size_t)N * 4);
    unsigned*       bin   = (unsigned*)carve((size_t)E * 4);
    int*            cnt   = (int*)carve((size_t)NBA * NB * 4);
    int*            offsT = (int*)carve((size_t)NB * NBA * 4);
    int*            total = (int*)carve((size_t)NB * 4);
    int*            base  = (int*)carve((size_t)(NB + 1) * 4);
    int*            csr   = (int*)carve((size_t)E * 4);
    int*            roff  = (int*)carve((size_t)(N + 1) * 4);
    unsigned short* h1b   = (unsigned short*)carve((size_t)N * HID * 2);
    unsigned short* zb    = (unsigned short*)carve((size_t)N * HID * 2);
    uint4*          bfragg= (uint4*)carve((size_t)16 * 64 * 16);
    (void)ws_size; (void)n_in; (void)out_size;

    k_a1   <<<NBA, 256, 0, stream>>>(dst, cnt, E, NB, chunk);
    k_a2a  <<<NB, NBA, 0, stream>>>(cnt, offsT, total, NB);
    k_a2b  <<<1, 1024, 0, stream>>>(total, base, NB);
    k_a3   <<<NBA, 256, 0, stream>>>(src, dst, offsT, base, bin, E, NB, chunk);
    k_sortb<<<NB, 256, 0, stream>>>(bin, base, csr, roff, dinv, N);
    k_prew <<<16, 64, 0, stream>>>(W1, bfragg);
    k_gemm1m<<<(N + 63) / 64, 64, 0, stream>>>(x, bfragg, dinv, h1b, N);
    k_agg  <<<(N * 64 + 255) / 256, 256, 0, stream>>>((const unsigned*)h1b, csr, roff,
                                                      dinv, b1, (unsigned*)zb, N);
    k_out  <<<(nOut * 64 + 255) / 256, 256, 0, stream>>>(zb, csr, roff, dinv, W2, b2, out, nOut);
}

// Round 11
// 182.893 us; speedup vs baseline: 3.2459x; 1.1011x over previous
//
#include <hip/hip_runtime.h>
#include <cstdint>
#include <math.h>

#define F_IN 512
#define HID  16
#define NCLS 40
#define OUT_STRIDE 20
#define TB   256   // nodes per dst-bucket (bucket = dst >> 8)
#define NBA  256   // partition-phase blocks

typedef __attribute__((ext_vector_type(8))) short short8;
typedef __attribute__((ext_vector_type(4))) float f32x4;

__device__ inline unsigned short f2bf(float f) {      // RNE f32 -> bf16
    unsigned u = __float_as_uint(f);
    u += 0x7fff + ((u >> 16) & 1);
    return (unsigned short)(u >> 16);
}
__device__ inline float bf2f(unsigned short h) {
    return __uint_as_float(((unsigned)h) << 16);
}

// ---------- A1: per-block bucket histogram ----------
__global__ __launch_bounds__(256) void k_a1(const int* __restrict__ dst,
                                            int* __restrict__ cnt,
                                            int E, int NB, int chunk) {
    __shared__ int h[512];
    int t = threadIdx.x;
    for (int b = t; b < NB; b += 256) h[b] = 0;
    __syncthreads();
    int e0 = blockIdx.x * chunk, e1 = min(E, e0 + chunk);
    for (int e = e0 + t; e < e1; e += 256) {
        int d = __builtin_nontemporal_load(&dst[e]);
        atomicAdd(&h[d >> 8], 1);
    }
    __syncthreads();
    for (int b = t; b < NB; b += 256) cnt[(size_t)blockIdx.x * NB + b] = h[b];
}

// ---------- A2a: per-bucket exclusive scan across blocks ----------
__global__ __launch_bounds__(NBA) void k_a2a(const int* __restrict__ cnt,
                                             int* __restrict__ offsT,
                                             int* __restrict__ total, int NB) {
    __shared__ int s[NBA];
    int t = threadIdx.x, b = blockIdx.x;
    int v = cnt[(size_t)t * NB + b];
    s[t] = v;
    __syncthreads();
    for (int off = 1; off < NBA; off <<= 1) {
        int tmp = (t >= off) ? s[t - off] : 0;
        __syncthreads();
        s[t] += tmp;
        __syncthreads();
    }
    offsT[(size_t)b * NBA + t] = s[t] - v;
    if (t == NBA - 1) total[b] = s[t];
}

// ---------- A2b+Prew: bucket-base scan  +  W1 -> MFMA B-fragment pack ----------
// Single block, 1024 threads: scan NB totals into base[]; every thread also
// packs one of the 16*64 = 1024 B-fragments (independent work, no sync needed).
__global__ void k_a2bw(const int* __restrict__ total, int* __restrict__ base, int NB,
                       const float* __restrict__ W1, uint4* __restrict__ bfragg) {
    __shared__ int s[1024];
    int t = threadIdx.x;
    int v = (t < NB) ? total[t] : 0;
    s[t] = v;
    __syncthreads();
    for (int off = 1; off < 1024; off <<= 1) {
        int tmp = (t >= off) ? s[t - off] : 0;
        __syncthreads();
        s[t] += tmp;
        __syncthreads();
    }
    if (t < NB) base[t] = s[t] - v;
    if (t == NB - 1) base[NB] = s[t];

    // W1 prepack: bfragg[kstep*64+ln] = 8 bf16 of W1[k0..k0+7][col]
    int kstep = t >> 6, ln = t & 63;
    int col = ln & 15, k0 = kstep * 32 + (ln >> 4) * 8;
    unsigned up[4];
#pragma unroll
    for (int i = 0; i < 4; i++) {
        float a = W1[(k0 + 2 * i) * HID + col];
        float b = W1[(k0 + 2 * i + 1) * HID + col];
        up[i] = (unsigned)f2bf(a) | ((unsigned)f2bf(b) << 16);
    }
    bfragg[t] = make_uint4(up[0], up[1], up[2], up[3]);
}

// ---------- A3: stable partition scatter; per-block contiguous runs ----------
// chunk/NB ~ 32 edges -> ~128B runs per bucket per block: full-line writes.
__global__ __launch_bounds__(256) void k_a3(const int* __restrict__ src,
                                            const int* __restrict__ dst,
                                            const int* __restrict__ offsT,
                                            const int* __restrict__ base,
                                            unsigned* __restrict__ bin,
                                            int E, int NB, int chunk) {
    __shared__ int pos[512];
    int t = threadIdx.x, blk = blockIdx.x;
    for (int b = t; b < NB; b += 256) pos[b] = base[b] + offsT[(size_t)b * NBA + blk];
    __syncthreads();
    int e0 = blk * chunk, e1 = min(E, e0 + chunk);
    for (int e = e0 + t; e < e1; e += 256) {
        int d = __builtin_nontemporal_load(&dst[e]);
        int s = __builtin_nontemporal_load(&src[e]);
        int p = atomicAdd(&pos[d >> 8], 1);
        bin[p] = ((unsigned)s << 8) | (unsigned)(d & (TB - 1));
    }
}

// ---------- Sortb: in-bucket counting sort -> CSR + roff + dinv ----------
__global__ __launch_bounds__(256) void k_sortb(const unsigned* __restrict__ bin,
                                               const int* __restrict__ base,
                                               int* __restrict__ csr,
                                               int* __restrict__ roff,
                                               float* __restrict__ dinv, int N) {
    __shared__ int cnt[TB], incl[TB], pos[TB];
    int t = threadIdx.x, b = blockIdx.x;
    cnt[t] = 0;
    __syncthreads();
    int j0 = base[b], j1 = base[b + 1];
    for (int j = j0 + t; j < j1; j += 256)
        atomicAdd(&cnt[bin[j] & (TB - 1)], 1);
    __syncthreads();
    incl[t] = cnt[t];
    __syncthreads();
    for (int off = 1; off < TB; off <<= 1) {
        int v = (t >= off) ? incl[t - off] : 0;
        __syncthreads();
        incl[t] += v;
        __syncthreads();
    }
    int ex = incl[t] - cnt[t];
    pos[t] = ex;
    int node = b * TB + t;
    if (node < N) {
        roff[node] = j0 + ex;
        dinv[node] = rsqrtf((float)cnt[t] + 1.0f);  // +1 self loop
    } else if (node == N) {
        roff[N] = j0 + ex;
    }
    __syncthreads();
    for (int j = j0 + t; j < j1; j += 256) {
        unsigned v = bin[j];
        int p = atomicAdd(&pos[v & (TB - 1)], 1);
        csr[j0 + p] = (int)(v >> 8);
    }
}

// ---------- GEMM1 via MFMA, 1 wave / 64 rows, no LDS ----------
__global__ __launch_bounds__(64) void k_gemm1m(const float* __restrict__ x,
                                               const uint4* __restrict__ bfragg,
                                               const float* __restrict__ dinv,
                                               unsigned short* __restrict__ h1b, int n) {
    int lane = threadIdx.x;
    int rows0 = blockIdx.x * 64;
    int arow = lane & 15, kgrp = lane >> 4;

    const float* xr[4];
#pragma unroll
    for (int rt = 0; rt < 4; rt++) {
        int r = rows0 + rt * 16 + arow;
        if (r >= n) r = n - 1;                 // clamp loads; stores guarded
        xr[rt] = x + (size_t)r * F_IN + kgrp * 8;
    }

    f32x4 acc[4];
#pragma unroll
    for (int rt = 0; rt < 4; rt++) acc[rt] = (f32x4){0.f, 0.f, 0.f, 0.f};

#pragma unroll 4
    for (int kstep = 0; kstep < 16; kstep++) {
        uint4 braw = bfragg[kstep * 64 + lane];   // L2-resident broadcast
        short8 b;
        *(uint4*)&b = braw;
#pragma unroll
        for (int rt = 0; rt < 4; rt++) {
            float4 lo = *(const float4*)(xr[rt] + kstep * 32);
            float4 hi = *(const float4*)(xr[rt] + kstep * 32 + 4);
            short8 a;
            a[0] = (short)f2bf(lo.x); a[1] = (short)f2bf(lo.y);
            a[2] = (short)f2bf(lo.z); a[3] = (short)f2bf(lo.w);
            a[4] = (short)f2bf(hi.x); a[5] = (short)f2bf(hi.y);
            a[6] = (short)f2bf(hi.z); a[7] = (short)f2bf(hi.w);
            acc[rt] = __builtin_amdgcn_mfma_f32_16x16x32_bf16(a, b, acc[rt], 0, 0, 0);
        }
    }

    // C layout: row' = (lane>>4)*4 + r, col = lane&15
    int col = lane & 15, rbase = (lane >> 4) * 4;
#pragma unroll
    for (int rt = 0; rt < 4; rt++) {
#pragma unroll
        for (int r = 0; r < 4; r++) {
            int row = rows0 + rt * 16 + rbase + r;
            if (row < n)
                h1b[(size_t)row * HID + col] = f2bf(acc[rt][r] * dinv[row]);
        }
    }
}

// ---------- Agg: wave-per-node, 8x8, csr prefetch breaks load chain ----------
__global__ __launch_bounds__(256) void k_agg(const unsigned* __restrict__ h1u,
                                             const int* __restrict__ csr,
                                             const int* __restrict__ roff,
                                             const float* __restrict__ dinv,
                                             const float* __restrict__ b1,
                                             unsigned* __restrict__ zu, int n) {
    int lane = threadIdx.x & 63;
    int node = (blockIdx.x * blockDim.x + threadIdx.x) >> 6;  // one wave per node
    if (node >= n) return;
    int cp = lane & 7;        // col-pair: cols 2cp, 2cp+1
    int sub = lane >> 3;      // 8 subgroups -> 8 edges in flight
    int s0 = roff[node], s1 = roff[node + 1];
    float sa = 0.f, sb = 0.f;
    int j = s0 + sub;
    int nxt = (j < s1) ? csr[j] : 0;
    for (; j < s1; j += 8) {
        int cur = nxt;
        int jn = j + 8;
        if (jn < s1) nxt = csr[jn];       // overlaps with gather below
        unsigned u = h1u[(size_t)cur * 8 + cp];
        sa += bf2f((unsigned short)(u & 0xffff));
        sb += bf2f((unsigned short)(u >> 16));
    }
    sa += __shfl_xor(sa, 8);  sb += __shfl_xor(sb, 8);
    sa += __shfl_xor(sa, 16); sb += __shfl_xor(sb, 16);
    sa += __shfl_xor(sa, 32); sb += __shfl_xor(sb, 32);
    unsigned us = h1u[(size_t)node * 8 + cp];                 // self loop
    sa += bf2f((unsigned short)(us & 0xffff));
    sb += bf2f((unsigned short)(us >> 16));
    float dv = dinv[node];
    float pa = dv * sa + b1[2 * cp];
    float pb = dv * sb + b1[2 * cp + 1];
    if (lane < 8) {
        unsigned short za = f2bf(fmaxf(pa, 0.f) * dv);
        unsigned short zbv = f2bf(fmaxf(pb, 0.f) * dv);
        zu[(size_t)node * 8 + cp] = (unsigned)za | ((unsigned)zbv << 16);
    }
}

// ---------- Out: layer-2 gather (rows %20 only) + matvec + log_softmax ----------
__global__ void k_out(const unsigned short* __restrict__ zb,
                      const int* __restrict__ csr, const int* __restrict__ roff,
                      const float* __restrict__ dinv, const float* __restrict__ W2,
                      const float* __restrict__ b2, float* __restrict__ out, int nOut) {
    int lane = threadIdx.x & 63;
    int wv = (blockIdx.x * blockDim.x + threadIdx.x) >> 6;  // one wave per out row
    if (wv >= nOut) return;
    int node = wv * OUT_STRIDE;
    int c = lane & 15, sub = lane >> 4;
    int s0 = roff[node], s1 = roff[node + 1];
    float sum = 0.f;
    for (int j = s0 + sub; j < s1; j += 4)
        sum += bf2f(zb[(size_t)csr[j] * HID + c]);
    sum += __shfl_xor(sum, 16);
    sum += __shfl_xor(sum, 32);
    sum += bf2f(zb[(size_t)node * HID + c]);  // self loop
    float a = dinv[node] * sum;

    int jj = lane < NCLS ? lane : 0;
    float v = 0.f;
#pragma unroll
    for (int cc = 0; cc < 16; cc++) {
        float ac = __shfl(a, cc);  // lane cc holds column cc
        v = fmaf(ac, W2[cc * NCLS + jj], v);
    }
    v += b2[jj];

    float vm = lane < NCLS ? v : -INFINITY;
    for (int off = 1; off < 64; off <<= 1) vm = fmaxf(vm, __shfl_xor(vm, off));
    float ex = lane < NCLS ? expf(v - vm) : 0.f;
    float se = ex;
    for (int off = 1; off < 64; off <<= 1) se += __shfl_xor(se, off);
    float ls = logf(se);
    if (lane < NCLS) out[(size_t)wv * NCLS + lane] = v - vm - ls;
}

// ---------------- host launcher ----------------
extern "C" void kernel_launch(void* const* d_in, const int* in_sizes, int n_in,
                              void* d_out, int out_size, void* d_ws, size_t ws_size,
                              hipStream_t stream) {
    const int E = in_sizes[0] / 2;
    const int N = in_sizes[1] / F_IN;
    const int nOut = (N + OUT_STRIDE - 1) / OUT_STRIDE;
    const int NB = (N + TB - 1) / TB;                 // 391
    const int chunk = (E + NBA - 1) / NBA;

    const int* src = (const int*)d_in[0];
    const int* dst = src + E;
    const float* x  = (const float*)d_in[1];
    const float* W1 = (const float*)d_in[2];
    const float* b1 = (const float*)d_in[3];
    const float* W2 = (const float*)d_in[4];
    const float* b2 = (const float*)d_in[5];
    float* out = (float*)d_out;

    uint8_t* w = (uint8_t*)d_ws;
    size_t off = 0;
    auto carve = [&](size_t bytes) {
        void* p = w + off;
        off += (bytes + 15) & ~(size_t)15;
        return p;
    };
    float*          dinv  = (float*)carve((size_t)N * 4);
    unsigned*       bin   = (unsigned*)carve((size_t)E * 4);
    int*            cnt   = (int*)carve((size_t)NBA * NB * 4);
    int*            offsT = (int*)carve((size_t)NB * NBA * 4);
    int*            total = (int*)carve((size_t)NB * 4);
    int*            base  = (int*)carve((size_t)(NB + 1) * 4);
    int*            csr   = (int*)carve((size_t)E * 4);
    int*            roff  = (int*)carve((size_t)(N + 1) * 4);
    unsigned short* h1b   = (unsigned short*)carve((size_t)N * HID * 2);
    unsigned short* zb    = (unsigned short*)carve((size_t)N * HID * 2);
    uint4*          bfragg= (uint4*)carve((size_t)16 * 64 * 16);
    (void)ws_size; (void)n_in; (void)out_size;

    k_a1   <<<NBA, 256, 0, stream>>>(dst, cnt, E, NB, chunk);
    k_a2a  <<<NB, NBA, 0, stream>>>(cnt, offsT, total, NB);
    k_a2bw <<<1, 1024, 0, stream>>>(total, base, NB, W1, bfragg);
    k_a3   <<<NBA, 256, 0, stream>>>(src, dst, offsT, base, bin, E, NB, chunk);
    k_sortb<<<NB, TB, 0, stream>>>(bin, base, csr, roff, dinv, N);
    k_gemm1m<<<(N + 63) / 64, 64, 0, stream>>>(x, bfragg, dinv, h1b, N);
    k_agg  <<<(N * 64 + 255) / 256, 256, 0, stream>>>((const unsigned*)h1b, csr, roff,
                                                      dinv, b1, (unsigned*)zb, N);
    k_out  <<<(nOut * 64 + 255) / 256, 256, 0, stream>>>(zb, csr, roff, dinv, W2, b2, out, nOut);
}